// Round 5
// baseline (220.235 us; speedup 1.0000x reference)
//
#include <hip/hip_runtime.h>
#include <hip/hip_bf16.h>

#define NN 384
#define NP 147456   // N*N

using short8 = __attribute__((ext_vector_type(8))) short;
using f32x4  = __attribute__((ext_vector_type(4))) float;

#define DEV static __device__ __forceinline__

// ---------------- small helpers ----------------
DEV unsigned short f2b(float f){               // f32 -> bf16 (RNE)
  unsigned int u = __float_as_uint(f);
  u += 0x7FFFu + ((u >> 16) & 1u);
  return (unsigned short)(u >> 16);
}
DEV float exp_e(float x){ return __builtin_amdgcn_exp2f(x * 1.4426950408889634f); }
DEV float tanh_f(float x){
  float e = exp_e(2.0f * x);
  return 1.0f - 2.0f * __builtin_amdgcn_rcpf(e + 1.0f);
}

typedef const void __attribute__((address_space(1)))* gas_ptr;
typedef void       __attribute__((address_space(3)))* las_ptr;
DEV void gload16(const void* g, void* l){
  __builtin_amdgcn_global_load_lds((gas_ptr)g, (las_ptr)l, 16, 0, 0);
}

DEV int frag_off(int r, int lane){
  return r * 64 + ((((lane >> 4) ^ ((r >> 1) & 3)) & 3) << 4);
}

// ---------------- setup: gather+mean AND all weight reformat in ONE launch --
__global__ __launch_bounds__(256) void setup_kernel(
    const float* __restrict__ feats, const int* __restrict__ vid_idx,
    const int* __restrict__ starts, float* __restrict__ outClip,
    float* __restrict__ outMask, unsigned short* __restrict__ evb,
    const float* __restrict__ Wpre, const float* __restrict__ Wq,
    const float* __restrict__ Wk,   const float* __restrict__ Wv,
    const float* __restrict__ W1,   const float* __restrict__ W2,
    const float* __restrict__ bq,   const float* __restrict__ bk,
    const float* __restrict__ bv,
    unsigned short* __restrict__ WTpre, unsigned short* __restrict__ WTqkv,
    unsigned short* __restrict__ W1F,   unsigned short* __restrict__ W2F,
    float* __restrict__ bqkv)
{
  __shared__ float tile[64][65];
  int bid = blockIdx.x, tid = threadIdx.x;
  if(bid < 384){
    int p = bid;
    int vid = vid_idx[p], st = starts[p];
    const float4* base = (const float4*)feats + ((long)vid * 256 + st) * 256;
    float4* oc = (float4*)outClip + (long)p * 16 * 256;
    float4 acc = make_float4(0.f, 0.f, 0.f, 0.f);
#pragma unroll
    for(int l = 0; l < 16; ++l){
      float4 v = base[l * 256 + tid];
      oc[l * 256 + tid] = v;
      acc.x += v.x; acc.y += v.y; acc.z += v.z; acc.w += v.w;
    }
    float den = 16.0f + 1e-5f;
    unsigned short* d = evb + (long)p * 1024 + tid * 4;
    d[0] = f2b(acc.x / den); d[1] = f2b(acc.y / den);
    d[2] = f2b(acc.z / den); d[3] = f2b(acc.w / den);
    if(tid < 16) outMask[p * 16 + tid] = 1.0f;
    return;
  }
  int id = bid - 384;
  if(id == 384){
    for(int i = tid; i < 8192; i += 256){
      int kk = i >> 9, l = (i >> 3) & 63, e = i & 7;
      int k = kk * 32 + ((l >> 4) << 3) + e, g = l & 15;
      W2F[i] = (g < 8) ? f2b(W2[k * 8 + g]) : (unsigned short)0;
    }
    for(int i = tid; i < 512; i += 256){
      bqkv[i] = bq[i]; bqkv[512 + i] = bk[i]; bqkv[1024 + i] = bv[i];
    }
    return;
  }
  if(id >= 320){   // W1F: B-frag layout, [kk][cb][lane][e]
    int base = (id - 320) * 4096;
#pragma unroll
    for(int j = 0; j < 16; ++j){
      int i = base + j * 256 + tid;
      int e = i & 7, l = (i >> 3) & 63, cbkk = i >> 9;
      int cb = cbkk & 31, kk = cbkk >> 5;
      int k = kk * 32 + ((l >> 4) << 3) + e;
      int col = cb * 16 + (l & 15);
      W1F[i] = f2b(W1[(long)k * 512 + col]);
    }
    return;
  }
  const float* src; unsigned short* dst; int K, C, k0, c0;
  if(id < 128){ src = Wpre; dst = WTpre; K = 1024; C = 512;
                k0 = (id >> 3) * 64; c0 = (id & 7) * 64; }
  else { int l = id - 128; int which = l >> 6; int r = l & 63;
         src = which == 0 ? Wq : (which == 1 ? Wk : Wv);
         dst = WTqkv + which * 512 * 512; K = 512; C = 512;
         k0 = (r >> 3) * 64; c0 = (r & 7) * 64; }
#pragma unroll
  for(int i = 0; i < 16; ++i){
    int idx = tid + i * 256, r = idx >> 6, c = idx & 63;
    tile[r][c] = src[(long)(k0 + r) * C + c0 + c];
  }
  __syncthreads();
#pragma unroll
  for(int i = 0; i < 16; ++i){
    int idx = tid + i * 256, r = idx >> 6, c = idx & 63;
    dst[(long)(c0 + r) * K + k0 + c] = f2b(tile[c][r]);
  }
}

// ------- 64xK @ Kx128 bf16 MFMA GEMM, 4 waves, 4-deep counted pipeline -----
__global__ __launch_bounds__(256, 1) void gemmN128(
    const unsigned short* __restrict__ A, const int* __restrict__ gidx,
    const unsigned short* __restrict__ BT, const float* __restrict__ bias,
    float* __restrict__ Cf, unsigned short* __restrict__ Cb,
    int K, int ldc, int relu)
{
  __shared__ unsigned short sA[4][64 * 32];    // 16 KB
  __shared__ unsigned short sB[4][128 * 32];   // 32 KB
  const int tid = threadIdx.x, lane = tid & 63, w = tid >> 6;
  const int r0 = blockIdx.x * 64, c0 = blockIdx.y * 128;
  const int nk = K >> 5;

  int rA = w * 16 + (lane >> 2);
  int gsltA = (lane & 3) ^ ((rA >> 1) & 3);
  int arow = gidx ? gidx[r0 + rA] : (r0 + rA);
  const unsigned short* srcA = A + (long)arow * K + gsltA * 8;

  int rB0 = (w * 2) * 16 + (lane >> 2), rB1 = (w * 2 + 1) * 16 + (lane >> 2);
  const unsigned short* srcB0 = BT + (long)(c0 + rB0) * K + (((lane & 3) ^ ((rB0 >> 1) & 3)) * 8);
  const unsigned short* srcB1 = BT + (long)(c0 + rB1) * K + (((lane & 3) ^ ((rB1 >> 1) & 3)) * 8);

  auto STAGE = [&](int kk){
    int buf = kk & 3;
    int ko = kk * 32;
    gload16(srcB0 + ko, (char*)sB[buf] + (w * 2    ) * 1024);
    gload16(srcB1 + ko, (char*)sB[buf] + (w * 2 + 1) * 1024);
    gload16(srcA  + ko, (char*)sA[buf] + w * 1024);
  };

  f32x4 acc[4][2];
#pragma unroll
  for(int i = 0; i < 4; ++i)
#pragma unroll
    for(int j = 0; j < 2; ++j) acc[i][j] = (f32x4){0.f, 0.f, 0.f, 0.f};

  STAGE(0); STAGE(1); STAGE(2);   // 9 loads/thread in flight

  for(int kk = 0; kk < nk; ++kk){
    int cur = kk & 3;
    if(kk < nk - 2)       asm volatile("s_waitcnt vmcnt(6)" ::: "memory");
    else if(kk == nk - 2) asm volatile("s_waitcnt vmcnt(3)" ::: "memory");
    else                  asm volatile("s_waitcnt vmcnt(0)" ::: "memory");
    __builtin_amdgcn_s_barrier();

    short8 af[4], bfv[2];
#pragma unroll
    for(int mi = 0; mi < 4; ++mi)
      af[mi] = *(const short8*)((const char*)sA[cur] + frag_off(mi * 16 + (lane & 15), lane));
#pragma unroll
    for(int ni = 0; ni < 2; ++ni)
      bfv[ni] = *(const short8*)((const char*)sB[cur] + frag_off(w * 32 + ni * 16 + (lane & 15), lane));

    if(kk + 3 < nk) STAGE(kk + 3);

#pragma unroll
    for(int mi = 0; mi < 4; ++mi)
#pragma unroll
      for(int ni = 0; ni < 2; ++ni)
        acc[mi][ni] = __builtin_amdgcn_mfma_f32_16x16x32_bf16(af[mi], bfv[ni], acc[mi][ni], 0, 0, 0);
  }

#pragma unroll
  for(int ni = 0; ni < 2; ++ni){
    int c = c0 + w * 32 + ni * 16 + (lane & 15);
    float bv = bias ? bias[c] : 0.f;
#pragma unroll
    for(int mi = 0; mi < 4; ++mi){
      int rbase = r0 + mi * 16 + ((lane >> 4) << 2);
#pragma unroll
      for(int r = 0; r < 4; ++r){
        float v = acc[mi][ni][r] + bv;
        if(relu) v = fmaxf(v, 0.f);
        Cf[(long)(rbase + r) * ldc + c] = v;
        if(Cb) Cb[(long)(rbase + r) * ldc + c] = f2b(v);
      }
    }
  }
}

// -------- pos_sim: trig of tile t+1 folded into MFMA loop of tile t --------
// 1 block/CU, 128 KB LDS (double-buffered pe), 3 barriers/tile.
__global__ __launch_bounds__(512, 1) void pos_sim_kernel(
    const unsigned short* __restrict__ W1F, const float* __restrict__ b1,
    const unsigned short* __restrict__ W2F, const float* __restrict__ b2,
    const float* __restrict__ ts, float* __restrict__ sim)
{
  __shared__ unsigned short pe0[16][2048];   // 64 KB
  __shared__ unsigned short pe1[16][2048];   // 64 KB
  const int tid = threadIdx.x, lane = tid & 63, w = tid >> 6;
  const int jt = tid & 7, prow = tid >> 3;
  const int swzp = (prow >> 1) & 3;
  const float inv2pi = 0.15915494309189535f;
  const float kexp = -0.10381025296523f;

  float b1v[4];
#pragma unroll
  for(int ni = 0; ni < 4; ++ni) b1v[ni] = b1[w * 64 + ni * 16 + (lane & 15)];
  const float b2v = b2[lane & 7];

  // write sin/cos for column-slot (jt,kk) of a pe tile (rows = prow)
  auto trigj = [&](unsigned short* buf, float a, float b, int kk){
    int j = jt * 16 + kk;                    // j in [0,128)
    float wjv = __builtin_amdgcn_exp2f(kexp * (float)j);
    float ra = __builtin_amdgcn_fractf(a * wjv * inv2pi);
    float rb = __builtin_amdgcn_fractf(b * wjv * inv2pi);
    unsigned short sa = f2b(__builtin_amdgcn_sinf(ra));
    unsigned short ca = f2b(__builtin_amdgcn_cosf(ra));
    unsigned short sb = f2b(__builtin_amdgcn_sinf(rb));
    unsigned short cb = f2b(__builtin_amdgcn_cosf(rb));
    int lowoff = prow * 64 + (((((j >> 3) & 3) ^ swzp)) << 4) + (j & 7) * 2;
    int ch = j >> 5;
    char* p = (char*)buf;
    *(unsigned short*)(p + (ch     ) * 4096 + lowoff) = sa;   // sin(a·wj)
    *(unsigned short*)(p + (ch +  4) * 4096 + lowoff) = ca;   // cos(a·wj)
    *(unsigned short*)(p + (ch +  8) * 4096 + lowoff) = sb;   // sin(b·wj)
    *(unsigned short*)(p + (ch + 12) * 4096 + lowoff) = cb;   // cos(b·wj)
  };
  auto getab = [&](int t, float& a, float& b){
    int p = t * 64 + prow;
    int n = p / NN, m = p - n * NN;
    float sn = ts[2*n], en = ts[2*n+1], sm = ts[2*m], em = ts[2*m+1];
    float cn = 0.5f*(sn+en), cm = 0.5f*(sm+em);
    float ln = fmaxf(en-sn, 0.1f), lm = fmaxf(em-sm, 0.1f);
    a = 100.0f * (cn - cm) / ln;
    b = 100.0f * 0.69314718055994531f * __builtin_amdgcn_logf(lm / ln);
  };

  const int t0 = blockIdx.x * 9;
  { // prologue: full trig of first tile into pe0
    float a, b; getab(t0, a, b);
#pragma unroll
    for(int kk = 0; kk < 16; ++kk) trigj(&pe0[0][0], a, b, kk);
  }

  for(int ti = 0; ti < 9; ++ti){
    const int t = t0 + ti;
    unsigned short* bufC = (ti & 1) ? &pe1[0][0] : &pe0[0][0];
    unsigned short* bufN = (ti & 1) ? &pe0[0][0] : &pe1[0][0];
    const int p0 = t * 64;
    const bool hasNext = (ti < 8);
    float aN = 0.f, bN = 0.f;
    if(hasNext) getab(t + 1, aN, bN);

    // barrier 1: trig writes of bufC complete; prev W2 reads of bufN done
    asm volatile("s_waitcnt lgkmcnt(0)" ::: "memory");
    __builtin_amdgcn_s_barrier();

    f32x4 acc[4][4];
#pragma unroll
    for(int i = 0; i < 4; ++i)
#pragma unroll
      for(int j = 0; j < 4; ++j) acc[i][j] = (f32x4){0.f, 0.f, 0.f, 0.f};

    for(int kk = 0; kk < 16; ++kk){
      short8 af[4], bfv[4];
#pragma unroll
      for(int ni = 0; ni < 4; ++ni)
        bfv[ni] = *(const short8*)(W1F + (((kk * 32 + (w * 4 + ni)) * 64 + lane) << 3));
#pragma unroll
      for(int mi = 0; mi < 4; ++mi)
        af[mi] = *(const short8*)((const char*)bufC + kk * 4096 + frag_off(mi * 16 + (lane & 15), lane));
      if(hasNext) trigj(bufN, aN, bN, kk);   // VALU/trans overlaps matrix pipe
      __builtin_amdgcn_s_setprio(1);
#pragma unroll
      for(int mi = 0; mi < 4; ++mi)
#pragma unroll
        for(int ni = 0; ni < 4; ++ni)
          acc[mi][ni] = __builtin_amdgcn_mfma_f32_16x16x32_bf16(af[mi], bfv[ni], acc[mi][ni], 0, 0, 0);
      __builtin_amdgcn_s_setprio(0);
    }
    // barrier 2: bufC reads done (tanh may overwrite), bufN trig complete
    asm volatile("s_waitcnt lgkmcnt(0)" ::: "memory");
    __builtin_amdgcn_s_barrier();

    // tanh(S + b1) -> bf16 back into bufC
#pragma unroll
    for(int ni = 0; ni < 4; ++ni){
      int h = w * 64 + ni * 16 + (lane & 15);
      int ch = h >> 5;
      int kb = (h & 31) * 2;
#pragma unroll
      for(int mi = 0; mi < 4; ++mi){
#pragma unroll
        for(int r = 0; r < 4; ++r){
          int row = mi * 16 + ((lane >> 4) << 2) + r;
          float tv = tanh_f(acc[mi][ni][r] + b1v[ni]);
          *(unsigned short*)((char*)bufC + ch * 4096 + row * 64 + (kb ^ (((row >> 1) & 3) << 4))) = f2b(tv);
        }
      }
    }
    // barrier 3: tanh tile ready for W2
    asm volatile("s_waitcnt lgkmcnt(0)" ::: "memory");
    __builtin_amdgcn_s_barrier();

    // W2 via MFMA: waves 0-3 (wave = mi); sim = result + b2
    if(w < 4){
      f32x4 acc2 = (f32x4){0.f, 0.f, 0.f, 0.f};
      for(int kk = 0; kk < 16; ++kk){
        short8 af2  = *(const short8*)((const char*)bufC + kk * 4096 + frag_off(w * 16 + (lane & 15), lane));
        short8 w2fk = *(const short8*)(W2F + ((kk * 64 + lane) << 3));
        acc2 = __builtin_amdgcn_mfma_f32_16x16x32_bf16(af2, w2fk, acc2, 0, 0, 0);
      }
      if((lane & 15) < 8){
        int g = lane & 15;
        int rbase = w * 16 + ((lane >> 4) << 2);
#pragma unroll
        for(int r = 0; r < 4; ++r)
          sim[(long)g * NP + p0 + rbase + r] = acc2[r] + b2v;
      }
    }
    // no trailing barrier: next iteration's barrier 1 orders W2 reads
    // against the next trig writes into this buffer.
  }
}

// ---------------- attn (+cos_sim fused) + tail ----------------
__global__ __launch_bounds__(512) void attn_tail_kernel(
    const float* __restrict__ sim, const float* __restrict__ qkv,
    const float* __restrict__ ef, const int* __restrict__ gidx,
    const float* __restrict__ ts, const float* __restrict__ dur,
    float* __restrict__ out)
{
  int n = blockIdx.x, tid = threadIdx.x, g = tid >> 6, lane = tid & 63;
  __shared__ float w32s[8][32];
  float4 q[16];
  const float4* qr = (const float4*)(qkv + (long)n * 1536 + g * 64);
#pragma unroll
  for(int d = 0; d < 16; ++d) q[d] = qr[d];
  const float* srow = sim + (long)g * NP + (long)n * NN;

  float sv[6], e[6], mx = -1e30f;
#pragma unroll
  for(int i = 0; i < 6; ++i){
    int m = lane + i * 64;
    const float4* kr = (const float4*)(qkv + (long)m * 1536 + 512 + g * 64);
    float ax = 0.f, ay = 0.f, az = 0.f, aw = 0.f;
#pragma unroll
    for(int d = 0; d < 16; ++d){
      float4 kv = kr[d];
      ax = fmaf(q[d].x, kv.x, ax); ay = fmaf(q[d].y, kv.y, ay);
      az = fmaf(q[d].z, kv.z, az); aw = fmaf(q[d].w, kv.w, aw);
    }
    sv[i] = (ax + ay + az + aw) * 0.125f + srow[m];
    mx = fmaxf(mx, sv[i]);
  }
#pragma unroll
  for(int o = 32; o > 0; o >>= 1) mx = fmaxf(mx, __shfl_xor(mx, o));
  float Z = 0.f;
#pragma unroll
  for(int i = 0; i < 6; ++i){ e[i] = exp_e(sv[i] - mx); Z += e[i]; }
#pragma unroll
  for(int o = 32; o > 0; o >>= 1) Z += __shfl_xor(Z, o);
  int m0 = (n >> 5) << 5;
  float ms = 0.f;
#pragma unroll
  for(int i = 0; i < 6; ++i){ int m = lane + i * 64; if(m >= m0 && m < m0 + 32) ms += e[i]; }
#pragma unroll
  for(int o = 32; o > 0; o >>= 1) ms += __shfl_xor(ms, o);
  float inv = 1.0f / (1e-5f * Z + ms);
#pragma unroll
  for(int i = 0; i < 6; ++i){ int m = lane + i * 64; if(m >= m0 && m < m0 + 32) w32s[g][m - m0] = e[i] * inv; }
  __syncthreads();
  float a = 0.f;
#pragma unroll 8
  for(int j = 0; j < 32; ++j)
    a = fmaf(w32s[g][j], qkv[(long)(m0 + j) * 1536 + 1024 + g * 64 + lane], a);
  out[(long)n * 1124 + g * 64 + lane] = fmaxf(a, 0.f);

  int pidx = gidx[n];
  out[(long)n * 1124 + 512 + tid] = ef[(long)pidx * 512 + tid];
  if(tid < 100){
    float d = dur[n];
    int si = (int)(ts[2 * n]     / d * 99.0f); si = min(si, 99);
    int ei = (int)(ts[2 * n + 1] / d * 99.0f); ei = min(ei, 99);
    out[(long)n * 1124 + 1024 + tid] = (tid >= si && tid <= ei) ? 1.0f : 0.0f;
  }
}

// ---------------- host launcher ----------------
extern "C" void kernel_launch(void* const* d_in, const int* in_sizes, int n_in,
                              void* d_out, int out_size, void* d_ws, size_t ws_size,
                              hipStream_t stream)
{
  const float* feats   = (const float*)d_in[0];
  const int*   vid_idx = (const int*)d_in[1];
  const int*   starts  = (const int*)d_in[2];
  const int*   gidx    = (const int*)d_in[4];
  const float* ts      = (const float*)d_in[6];
  const float* dur     = (const float*)d_in[7];
  const float* W_pre   = (const float*)d_in[8];
  const float* b_pre   = (const float*)d_in[9];
  const float* W_q     = (const float*)d_in[10];
  const float* b_q     = (const float*)d_in[11];
  const float* W_k     = (const float*)d_in[12];
  const float* b_k     = (const float*)d_in[13];
  const float* W_v     = (const float*)d_in[14];
  const float* b_v     = (const float*)d_in[15];
  const float* W_p1    = (const float*)d_in[16];
  const float* b_p1    = (const float*)d_in[17];
  const float* W_p2    = (const float*)d_in[18];
  const float* b_p2    = (const float*)d_in[19];

  float* out     = (float*)d_out;
  float* outClip = out + 431616;
  float* outMask = out + 6723072;

  char* ws = (char*)d_ws;
  size_t off = 0;
  auto alloc = [&](size_t bytes){ void* p = ws + off; off = (off + bytes + 255) & ~(size_t)255; return p; };
  unsigned short* evb   = (unsigned short*)alloc(384 * 1024 * 2);
  unsigned short* WTpre = (unsigned short*)alloc(512 * 1024 * 2);
  unsigned short* WTqkv = (unsigned short*)alloc((size_t)1536 * 512 * 2);
  unsigned short* W1F   = (unsigned short*)alloc(262144 * 2);
  unsigned short* W2F   = (unsigned short*)alloc(8192 * 2);
  float*  bqkv = (float*)alloc(1536 * 4);
  float*  ef   = (float*)alloc(384 * 512 * 4);
  unsigned short* efb = (unsigned short*)alloc(384 * 512 * 2);
  float*  qkv  = (float*)alloc((size_t)384 * 1536 * 4);
  float*  sim  = (float*)alloc((size_t)8 * NP * 4);

  setup_kernel<<<dim3(769), dim3(256), 0, stream>>>(
      feats, vid_idx, starts, outClip, outMask, evb,
      W_pre, W_q, W_k, W_v, W_p1, W_p2, b_q, b_k, b_v,
      WTpre, WTqkv, W1F, W2F, bqkv);
  gemmN128<<<dim3(6, 4), dim3(256), 0, stream>>>(evb, (const int*)nullptr, WTpre, b_pre, ef, efb, 1024, 512, 1);
  gemmN128<<<dim3(6, 12), dim3(256), 0, stream>>>(efb, gidx, WTqkv, bqkv, qkv, (unsigned short*)nullptr, 512, 1536, 0);
  pos_sim_kernel<<<dim3(256), dim3(512), 0, stream>>>(W1F, b_p1, W2F, b_p2, ts, sim);
  attn_tail_kernel<<<dim3(384), dim3(512), 0, stream>>>(sim, qkv, ef, gidx, ts, dur, out);
}